// Round 7
// baseline (240.708 us; speedup 1.0000x reference)
//
#include <hip/hip_runtime.h>
#include <float.h>

// VectorQuantizer: B=16,T=4096,D=256,K=1024 fp32.
// Round 9: OCCUPANCY + EPILOGUE pass. Rounds 3/5/6 all pinned at ~81-87us,
//   MfmaUtil ~15-16%: grid (512 blocks) capped residency at 2 waves/SIMD —
//   ~47us of bare latency stall on a 17us-MFMA + 16us-VALU workload.
//   (1) 64-token blocks -> grid 1024, ti=2 -> bfrag 64 VGPR, launch_bounds
//       (256,3) -> 3 waves/SIMD (12/CU), 1.5x latency-hiding.
//   (2) epilogue: per-chunk quad shfl-merges hoisted to ONE final merge
//       (top-2 merge is associative); per-element top-2 scan uses
//       index-in-mantissa packing: pv=(bits(v)&~127)|(127-j) -> 4 VALU ops,
//       no cmp/cndmask chains. <=127-ulp perturb (~8e-3) << 0.1 margin;
//       any tie it could misorder is margin-flagged -> exact rescue fixes it.
//   A-path = round-8 verified (tiled cht, afA/afB double-buffer, SLICE).
//   prep = r4 verified (tiled); rescue = r5 verified (8 tok/iter, grid 1024).
//   Score space: score = x.c - 0.5*c2  (argmin d2 == argmax score).

typedef _Float16 f16;
typedef f16 f16x8 __attribute__((ext_vector_type(8)));
typedef f16 f16x4 __attribute__((ext_vector_type(4)));
typedef float f32x4 __attribute__((ext_vector_type(4)));

#define DDIM    256
#define KCODES  1024
#define NTOK    65536
#define TOKB    64     // tokens per block
#define SMARGIN 0.1f   // score-space margin; == 0.2 in d2 units (d2 gap = 2*score gap)

// ---------------- prep: codebook fp32 -> A-fragment-tiled f16, c2, zero count ----
// Tiled layout: cht[((ct*8 + kt)*64 + L)*8 + j] = f16(cb[ct*16 + (L&15)][kt*32 + (L>>4)*8 + j])
//   (exactly the 16x16x32 MFMA A-operand per-lane layout; verified round 4)
__global__ __launch_bounds__(256) void vq_prep(const float* __restrict__ cb,
                                               f16* __restrict__ cht,
                                               float* __restrict__ c2,
                                               unsigned* __restrict__ count) {
    const int k    = blockIdx.x * 4 + (threadIdx.x >> 6);
    const int lane = threadIdx.x & 63;
    const float4 v = *(const float4*)(cb + (size_t)k * DDIM + 4 * lane);
    f16x4 h; h[0] = (f16)v.x; h[1] = (f16)v.y; h[2] = (f16)v.z; h[3] = (f16)v.w;
    const int ct = k >> 4, m = k & 15;
    const int e  = 4 * lane;            // this thread's 4 consecutive k-elements
    const int kt = e >> 5;
    const int s  = (e & 31) >> 3;       // sub-lane group within k-tile
    const int j0 = e & 7;               // 0 or 4
    const int L  = s * 16 + m;          // fragment lane
    *(f16x4*)(cht + ((size_t)(ct * 8 + kt) * 64 + L) * 8 + j0) = h;
    float ssum = v.x * v.x + v.y * v.y + v.z * v.z + v.w * v.w;
    #pragma unroll
    for (int off = 32; off > 0; off >>= 1) ssum += __shfl_down(ssum, off, 64);
    if (lane == 0) c2[k] = ssum;
    if (blockIdx.x == 0 && threadIdx.x == 0) *count = 0u;
}

// one k-slice: 8 MFMAs consuming CUR, then reload CUR with slice NS from NPTR
#define SLICE(CUR, S, NPTR, NS) do {                                                \
    _Pragma("unroll")                                                               \
    for (int ci = 0; ci < 4; ++ci)                                                  \
        _Pragma("unroll")                                                           \
        for (int ti = 0; ti < 2; ++ti)                                              \
            acc[ci][ti] = __builtin_amdgcn_mfma_f32_16x16x32_f16(                   \
                CUR[ci], bfrag[ti][S], acc[ci][ti], 0, 0, 0);                       \
    _Pragma("unroll")                                                               \
    for (int ci = 0; ci < 4; ++ci)                                                  \
        CUR[ci] = *(const f16x8*)((NPTR) + ci * 4096 + (NS) * 512);                 \
} while (0)

// ---------------- main: L2-streamed pipelined MFMA + packed argmax + gather -------
__global__ __launch_bounds__(256, 3) void vq_main(const float* __restrict__ xg,
                                                  const f16* __restrict__ cht,
                                                  const float* __restrict__ c2,
                                                  const float* __restrict__ cb,
                                                  float* __restrict__ out,
                                                  unsigned* __restrict__ count,
                                                  unsigned* __restrict__ list) {
    __shared__ float c2s[KCODES];
    __shared__ float wmv[2][TOKB];             // per code-half best (packed) score
    __shared__ int   wmi[2][TOKB];
    __shared__ float wms[2][TOKB];             // per code-half second (packed) score
    __shared__ int   idx_s[TOKB];

    const int t    = threadIdx.x;
    const int wave = t >> 6, lane = t & 63;
    const int wm   = wave >> 1;                // code-half (M)
    const int tn   = wave & 1;                 // token-half (N): 32 tokens
    const int q    = lane >> 4;                // operand quad
    const int m16  = lane & 15;
    const int tok0 = blockIdx.x * TOKB;

    // ---- c2 staging + the only pre-loop barrier (nothing outstanding) ----
    *(float4*)&c2s[t * 4] = *(const float4*)(c2 + t * 4);
    __syncthreads();

    const f16* aw = cht + wm * 16384 + lane * 8;   // wave's A-fragment base (r4 layout)

    // ---- issue chunk-0 slices 0,1 into the af double-buffer ----
    f16x8 afA[4], afB[4];
    #pragma unroll
    for (int ci = 0; ci < 4; ++ci) afA[ci] = *(const f16x8*)(aw + ci * 4096 + 0 * 512);
    #pragma unroll
    for (int ci = 0; ci < 4; ++ci) afB[ci] = *(const f16x8*)(aw + ci * 4096 + 1 * 512);

    // ---- load token B-fragments, fp32 -> f16 in registers (once; verified) ----
    f16x8 bfrag[2][8];
    #pragma unroll
    for (int ti = 0; ti < 2; ++ti) {
        const size_t row = (size_t)(tok0 + tn * 32 + ti * 16 + m16) * DDIM;
        #pragma unroll
        for (int ks = 0; ks < 8; ++ks) {
            const float* p = xg + row + ks * 32 + q * 8;
            const float4 u0 = *(const float4*)(p);
            const float4 u1 = *(const float4*)(p + 4);
            f16x8 b;
            b[0] = (f16)u0.x; b[1] = (f16)u0.y; b[2] = (f16)u0.z; b[3] = (f16)u0.w;
            b[4] = (f16)u1.x; b[5] = (f16)u1.y; b[6] = (f16)u1.z; b[7] = (f16)u1.w;
            bfrag[ti][ks] = b;
        }
    }

    // running top-2 per (lane, ti), PACKED: value bits with (127-j) in mantissa LSBs
    float rb1[2], rb2[2];
    #pragma unroll
    for (int ti = 0; ti < 2; ++ti) { rb1[ti] = -FLT_MAX; rb2[ti] = -FLT_MAX; }

    #pragma unroll 1
    for (int nc = 0; nc < 8; ++nc) {           // 8 chunks of 128 codes
        f32x4 acc[4][2];                       // [ci][ti], init = -0.5*c2 (score space)
        #pragma unroll
        for (int ci = 0; ci < 4; ++ci) {
            f32x4 cv = *(const f32x4*)&c2s[nc * 128 + wm * 64 + ci * 16 + q * 4];
            cv = cv * -0.5f;
            #pragma unroll
            for (int ti = 0; ti < 2; ++ti) acc[ci][ti] = cv;
        }

        const f16* an = aw + nc * 32768;
        const f16* ax = aw + ((nc + 1) & 7) * 32768;   // next chunk (wrap: dead loads)

        __builtin_amdgcn_s_setprio(1);
        SLICE(afA, 0, an, 2);                  // consume slice s, reload with s+2
        SLICE(afB, 1, an, 3);
        SLICE(afA, 2, an, 4);
        SLICE(afB, 3, an, 5);
        SLICE(afA, 4, an, 6);
        SLICE(afB, 5, an, 7);
        SLICE(afA, 6, ax, 0);                  // prefetch next chunk's slices 0,1
        SLICE(afB, 7, ax, 1);
        __builtin_amdgcn_s_setprio(0);

        // ---- per-lane packed top-2 scan (4 ops/elem, no index chains) ----
        // j = nc*16 + ci*4 + r ascends with code index within a lane's slice;
        // (127-j) in LSBs => on exact truncated ties, max picks lower j (lower c).
        #pragma unroll
        for (int ti = 0; ti < 2; ++ti) {
            #pragma unroll
            for (int ci = 0; ci < 4; ++ci) {
                #pragma unroll
                for (int r = 0; r < 4; ++r) {
                    const unsigned pv = (__float_as_uint(acc[ci][ti][r]) & ~127u)
                                        | (unsigned)(127 - (nc * 16 + ci * 4 + r));
                    const float pf = __uint_as_float(pv);
                    rb2[ti] = fmaxf(rb2[ti], fminf(rb1[ti], pf));  // old rb1
                    rb1[ti] = fmaxf(rb1[ti], pf);
                }
            }
        }
    }

    // ---- decode per-lane index (own q/wm), then ONE cross-quad merge ----
    #pragma unroll
    for (int ti = 0; ti < 2; ++ti) {
        const int jj = 127 - (int)(__float_as_uint(rb1[ti]) & 127u);
        int   i1 = (jj >> 4) * 128 + wm * 64 + ((jj >> 2) & 3) * 16 + q * 4 + (jj & 3);
        float b1 = rb1[ti], b2 = rb2[ti];
        #pragma unroll
        for (int sft = 0; sft < 2; ++sft) {    // merge quads (l^16, l^32)
            const int off = 16 << sft;
            const float ob1 = __shfl_xor(b1, off, 64);
            const float ob2 = __shfl_xor(b2, off, 64);
            const int   oi1 = __shfl_xor(i1, off, 64);
            const bool better = (ob1 > b1) || (ob1 == b1 && oi1 < i1);
            b2 = fmaxf(fmaxf(b2, ob2), fminf(b1, ob1));
            b1 = better ? ob1 : b1;
            i1 = better ? oi1 : i1;
        }
        if (lane < 16) {
            const int tl = tn * 32 + ti * 16 + m16;
            wmv[wm][tl] = b1; wmi[wm][tl] = i1; wms[wm][tl] = b2;
        }
    }
    __syncthreads();

    // ---- merge code-halves, flag, gather ----
    if (t < TOKB) {
        const float a1 = wmv[0][t], a2 = wms[0][t];
        const int   ai = wmi[0][t];
        const float b1_ = wmv[1][t], b2_ = wms[1][t];
        const int   bi_ = wmi[1][t];
        const bool bb = (b1_ > a1) || (b1_ == a1 && bi_ < ai);
        const float c1 = bb ? b1_ : a1;
        const int   ci_ = bb ? bi_ : ai;
        const float cs = fmaxf(fmaxf(a2, b2_), fminf(a1, b1_));
        idx_s[t] = ci_;
        if (c1 - cs < SMARGIN) {               // d2 gap = 2*(c1-cs) < 0.2
            const unsigned p = atomicAdd(count, 1u);
            list[p] = tok0 + t;
        }
    }
    __syncthreads();

    // gather epilogue: out[tok] = cb[argmin], coalesced float4
    #pragma unroll
    for (int i = 0; i < 16; ++i) {
        const int f   = i * 256 + t;           // 4096 float4 = 64 tok x 64
        const int tok = f >> 6, d4 = f & 63;
        const int code = idx_s[tok];
        const float4 v = *(const float4*)(cb + (size_t)code * DDIM + 4 * d4);
        *(float4*)(out + (size_t)(tok0 + tok) * DDIM + 4 * d4) = v;
    }
}

// ---------------- rescue: exact fp32 argmin for margin-flagged tokens ----------------
// (verified round 5: 8 tokens/iter, no spill, grid-stride 1024)
__global__ __launch_bounds__(256) void vq_rescue(const float* __restrict__ xg,
                                                 const float* __restrict__ cb,
                                                 const float* __restrict__ c2,
                                                 const unsigned* __restrict__ count,
                                                 const unsigned* __restrict__ list,
                                                 float* __restrict__ out) {
    __shared__ float xls[8][DDIM];             // 8 KB
    __shared__ float rv[4][8];
    __shared__ int   ri[4][8];
    __shared__ int   bidx[8];

    const int t = threadIdx.x;
    const int wave = t >> 6, lane = t & 63;
    const unsigned n = *count;

    for (unsigned base = blockIdx.x * 8; base < n; base += gridDim.x * 8) {
        const int nb = (int)min(8u, n - base);
        __syncthreads();                        // protect xls/rv/bidx reuse
        #pragma unroll
        for (int i = 0; i < 2; ++i) {
            const int f = t + 256 * i;          // 512 float4 slots
            const int row = f >> 6, d4 = f & 63;
            if (row < nb)
                *(float4*)&xls[row][4 * d4] =
                    *(const float4*)(xg + (size_t)list[base + row] * DDIM + 4 * d4);
        }
        __syncthreads();

        float acc[4][8];
        #pragma unroll
        for (int j = 0; j < 4; ++j)
            #pragma unroll
            for (int tk = 0; tk < 8; ++tk) acc[j][tk] = 0.0f;

        for (int d4 = 0; d4 < 64; ++d4) {
            float4 cv[4];
            #pragma unroll
            for (int j = 0; j < 4; ++j)
                cv[j] = *(const float4*)(cb + (size_t)(4 * t + j) * DDIM + 4 * d4);
            #pragma unroll
            for (int tk = 0; tk < 8; ++tk) {
                const float4 xv = *(const float4*)&xls[tk][4 * d4];
                #pragma unroll
                for (int j = 0; j < 4; ++j) {
                    float a = acc[j][tk];       // sequential .x->.w: verified order
                    a = fmaf(cv[j].x, xv.x, a);
                    a = fmaf(cv[j].y, xv.y, a);
                    a = fmaf(cv[j].z, xv.z, a);
                    a = fmaf(cv[j].w, xv.w, a);
                    acc[j][tk] = a;
                }
            }
        }

        // per-token argmin: thread's 4 codes -> wave butterfly -> cross-wave merge
        #pragma unroll
        for (int tk = 0; tk < 8; ++tk) {
            if (tk < nb) {
                float b1 = FLT_MAX; int i1 = 0;
                #pragma unroll
                for (int j = 0; j < 4; ++j) {   // codes 4t..4t+3 ascending
                    const float d = fmaf(-2.0f, acc[j][tk], c2[4 * t + j]);
                    if (d < b1) { b1 = d; i1 = 4 * t + j; }
                }
                #pragma unroll
                for (int off = 32; off > 0; off >>= 1) {
                    const float ov = __shfl_xor(b1, off, 64);
                    const int   oi = __shfl_xor(i1, off, 64);
                    if (ov < b1 || (ov == b1 && oi < i1)) { b1 = ov; i1 = oi; }
                }
                if (lane == 0) { rv[wave][tk] = b1; ri[wave][tk] = i1; }
            }
        }
        __syncthreads();
        if (t < 8 && t < nb) {                  // ascending wave order: same tiebreak
            float bv = rv[0][t]; int bi = ri[0][t];
            #pragma unroll
            for (int w = 1; w < 4; ++w)
                if (rv[w][t] < bv || (rv[w][t] == bv && ri[w][t] < bi)) {
                    bv = rv[w][t]; bi = ri[w][t];
                }
            bidx[t] = bi;
        }
        __syncthreads();

        #pragma unroll
        for (int i = 0; i < 2; ++i) {
            const int f = t + 256 * i;
            const int row = f >> 6, d4 = f & 63;
            if (row < nb) {
                const int code = bidx[row];
                const float4 v = *(const float4*)(cb + (size_t)code * DDIM + 4 * d4);
                *(float4*)(out + (size_t)list[base + row] * DDIM + 4 * d4) = v;
            }
        }
    }
}

extern "C" void kernel_launch(void* const* d_in, const int* in_sizes, int n_in,
                              void* d_out, int out_size, void* d_ws, size_t ws_size,
                              hipStream_t stream) {
    const float* x  = (const float*)d_in[0];   // [B,T,D] fp32
    const float* cb = (const float*)d_in[1];   // [K,D]   fp32
    float* out = (float*)d_out;

    char* ws = (char*)d_ws;
    f16*      cht   = (f16*)ws;                              // 524288 B (tiled)
    float*    c2    = (float*)(ws + 524288);                 // 4096 B
    unsigned* count = (unsigned*)(ws + 528448);              // 4 B (padded)
    unsigned* list  = (unsigned*)(ws + 528512);              // 262144 B

    hipLaunchKernelGGL(vq_prep,   dim3(KCODES / 4), dim3(256), 0, stream, cb, cht, c2, count);
    hipLaunchKernelGGL(vq_main,   dim3(NTOK / TOKB), dim3(256), 0, stream,
                       x, cht, c2, cb, out, count, list);
    hipLaunchKernelGGL(vq_rescue, dim3(1024),       dim3(256), 0, stream,
                       x, cb, c2, count, list, out);
}